// Round 12
// baseline (833.618 us; speedup 1.0000x reference)
//
#include <hip/hip_runtime.h>
#include <hip/hip_bf16.h>
#include <stdint.h>

// Problem constants (B=2, L=2048 -> T=4096 tokens)
#define T_TOK 4096
#define DDIM  1024
#define IDIM  4096
#define NEXP  8
// padded row count for gathered matrices (worst-case 256-tile overhang)
#define GROWS (T_TOK*2 + 256)

typedef __attribute__((ext_vector_type(8))) short bfrag;   // 8 bf16 (4 VGPR)
typedef __attribute__((ext_vector_type(4))) float f32x4;   // MFMA accum

__device__ __forceinline__ unsigned short f2bf(float x) {
    unsigned int u = __float_as_uint(x);
    unsigned int r = u + 0x7FFFu + ((u >> 16) & 1u);   // RNE
    return (unsigned short)(r >> 16);
}
__device__ __forceinline__ float bf2f(unsigned short h) {
    return __uint_as_float(((unsigned int)h) << 16);
}

// ---------------------------------------------------------------------------
// K1: per-token layernorm stats + xhat (bf16), fp32 router logits, top-2,
//     softmax -> per-slot weights; builds per-expert token lists via atomics.
// ---------------------------------------------------------------------------
__global__ __launch_bounds__(256) void router_kernel(
    const float* __restrict__ x,
    const float* __restrict__ rng, const float* __restrict__ rnb,
    const float* __restrict__ rw,  const float* __restrict__ rb,
    unsigned short* __restrict__ xhat,
    int* __restrict__ counts, int* __restrict__ tok_slot,
    float* __restrict__ wslot)
{
    const int t = blockIdx.x;
    const int tid = threadIdx.x;
    const int lane = tid & 63, wid = tid >> 6;

    float4 v = *(const float4*)(x + (size_t)t * DDIM + tid * 4);
    float s1 = v.x + v.y + v.z + v.w;
    float s2 = v.x*v.x + v.y*v.y + v.z*v.z + v.w*v.w;
    #pragma unroll
    for (int m = 32; m; m >>= 1) { s1 += __shfl_xor(s1, m, 64); s2 += __shfl_xor(s2, m, 64); }

    __shared__ float red[8];
    __shared__ float pl[4][8];
    __shared__ float bcast[2];
    if (lane == 0) { red[wid] = s1; red[wid + 4] = s2; }
    __syncthreads();
    if (tid == 0) {
        float S1 = red[0] + red[1] + red[2] + red[3];
        float S2 = red[4] + red[5] + red[6] + red[7];
        float mean = S1 * (1.f / 1024.f);
        float var  = S2 * (1.f / 1024.f) - mean * mean;
        bcast[0] = mean; bcast[1] = rsqrtf(var + 1e-5f);
    }
    __syncthreads();
    const float mean = bcast[0], rinv = bcast[1];

    float4 xh = { (v.x - mean) * rinv, (v.y - mean) * rinv,
                  (v.z - mean) * rinv, (v.w - mean) * rinv };
    ushort4 hx = { f2bf(xh.x), f2bf(xh.y), f2bf(xh.z), f2bf(xh.w) };
    *(ushort4*)(xhat + (size_t)t * DDIM + tid * 4) = hx;

    // router layernorm affine + logits (kept fp32 to match reference top-k)
    float4 g = *(const float4*)(rng + tid * 4);
    float4 b = *(const float4*)(rnb + tid * 4);
    float4 nm = { xh.x*g.x + b.x, xh.y*g.y + b.y, xh.z*g.z + b.z, xh.w*g.w + b.w };
    float p[8];
    #pragma unroll
    for (int e = 0; e < 8; e++) {
        float4 w = *(const float4*)(rw + e * DDIM + tid * 4);
        p[e] = nm.x*w.x + nm.y*w.y + nm.z*w.z + nm.w*w.w;
    }
    #pragma unroll
    for (int m = 32; m; m >>= 1) {
        #pragma unroll
        for (int e = 0; e < 8; e++) p[e] += __shfl_xor(p[e], m, 64);
    }
    if (lane == 0) {
        #pragma unroll
        for (int e = 0; e < 8; e++) pl[wid][e] = p[e];
    }
    __syncthreads();
    if (tid == 0) {
        float l[8];
        #pragma unroll
        for (int e = 0; e < 8; e++) l[e] = pl[0][e] + pl[1][e] + pl[2][e] + pl[3][e] + rb[e];
        int e0 = 0; float v0 = l[0];
        for (int e = 1; e < 8; e++) if (l[e] > v0) { v0 = l[e]; e0 = e; }
        int e1 = (e0 == 0) ? 1 : 0; float v1 = l[e1];
        for (int e = 0; e < 8; e++) if (e != e0 && l[e] > v1) { v1 = l[e]; e1 = e; }
        float ex = expf(v1 - v0);
        float w0 = 1.f / (1.f + ex);
        float w1 = ex * w0;
        int p0 = atomicAdd(&counts[e0], 1);
        tok_slot[e0 * T_TOK + p0] = (t << 1);
        int p1 = atomicAdd(&counts[e1], 1);
        tok_slot[e1 * T_TOK + p1] = (t << 1) | 1;
        wslot[t * 2]     = w0;
        wslot[t * 2 + 1] = w1;
    }
}

// K2: tiny exclusive prefix over 8 expert counts
__global__ void prefix_kernel(const int* __restrict__ counts, int* __restrict__ offs)
{
    if (threadIdx.x == 0) {
        int a = 0;
        for (int e = 0; e < 8; e++) { offs[e] = a; a += counts[e]; }
    }
}

// ---------------------------------------------------------------------------
// K3: build compacted per-expert A matrix: Agath[off[e]+pos][d] =
//     bf16( xhat[t][d]*ln_g[e][d] + ln_b[e][d] ), plus rowinfo for scatter.
// ---------------------------------------------------------------------------
__global__ __launch_bounds__(256) void gather_kernel(
    const unsigned short* __restrict__ xhat,
    const float* __restrict__ lng, const float* __restrict__ lnb,
    const int* __restrict__ counts, const int* __restrict__ offs,
    const int* __restrict__ tok_slot,
    unsigned short* __restrict__ Agath, int* __restrict__ rowinfo)
{
    const int e = blockIdx.y, pos = blockIdx.x;
    if (pos >= counts[e]) return;
    const int grow = offs[e] + pos;
    const int info = tok_slot[e * T_TOK + pos];
    if (threadIdx.x == 0) rowinfo[grow] = info;
    const int t = info >> 1;
    const int d = threadIdx.x * 4;
    ushort4 hx = *(const ushort4*)(xhat + (size_t)t * DDIM + d);
    float4 g = *(const float4*)(lng + (size_t)e * DDIM + d);
    float4 b = *(const float4*)(lnb + (size_t)e * DDIM + d);
    ushort4 o = { f2bf(bf2f(hx.x) * g.x + b.x),
                  f2bf(bf2f(hx.y) * g.y + b.y),
                  f2bf(bf2f(hx.z) * g.z + b.z),
                  f2bf(bf2f(hx.w) * g.w + b.w) };
    *(ushort4*)(Agath + (size_t)grow * DDIM + d) = o;
}

// ---------------------------------------------------------------------------
// K4: transpose+convert weights: W [E][Kd][Nd] fp32 -> WT [E][Nd][Kd] bf16.
// ---------------------------------------------------------------------------
__global__ __launch_bounds__(256) void transpose_kernel(
    const float* __restrict__ W, unsigned short* __restrict__ WT,
    int Kd, int Nd)
{
    const int e  = blockIdx.z;
    const int k0 = blockIdx.y * 64;
    const int n  = blockIdx.x * 256 + threadIdx.x;
    const float* src = W + (size_t)e * Kd * Nd + (size_t)k0 * Nd + n;
    unsigned short* dst = WT + ((size_t)e * Nd + n) * Kd + k0;
    unsigned short buf[64];
    #pragma unroll
    for (int j = 0; j < 64; j++)
        buf[j] = f2bf(src[(size_t)j * Nd]);
    #pragma unroll
    for (int c = 0; c < 8; c++)
        *(int4*)(dst + c * 8) = *(const int4*)(buf + c * 8);
}

// ---------------------------------------------------------------------------
// GEMM, reg-staged 2-phase pipeline, COALESCED loads + T2 XOR-swizzled LDS
// (the R11 pipeline with the addressing fixed — one-variable change):
//
//   Transport: lane l of wave w global_load_dwordx4's row w*16+m*8+(l>>3),
//   k-chunk (l&7)*16B -> 8 consecutive lanes read 128B CONTIGUOUS (R9-R11's
//   consume-order map scattered 64 lanes over 64 cache lines = ~2300 cyc of
//   L2 transactions per K-tile; that was the invariant-260us bottleneck).
//
//   LDS: plain row-major [128 rows][64 k] bf16 per operand per buffer, with
//   G4 XOR swizzle applied to the 16B-granule offset on BOTH sides:
//       byte(row, g) = row*128 + ((g*16) ^ ((row&7)<<4)),  g = k>>3
//   write side: each 8-lane group covers one full 128B row (conflict-free);
//   read side: 16-lanes-at-same-column becomes 2-way (free, m136).
//
//   Pipeline (unchanged from R11): 2 reg sets, 2 LDS buffers; loads for tile
//   t+2 issue at phase start, ds_write of t+1 after MFMAs, one
//   lgkmcnt(0)+s_barrier per K-tile, ZERO vmcnt drains in-loop.
//
// Grid: 1-D, e=b&7 (XCD pin), r=b>>3, mt0=r&7, nt=r>>3; persistent-mt loop.
// EPI=0: +b1, exact GELU -> H (bf16). EPI=1: +b2, *combine-w, atomicAdd out.
// ---------------------------------------------------------------------------
template<int EPI>
__global__ __launch_bounds__(512, 4) void gemm_kernel(
    const unsigned short* __restrict__ Asrc,
    const unsigned short* __restrict__ Bsrc,
    const float* __restrict__ bias,
    const int* __restrict__ counts,
    const int* __restrict__ offs,
    const int* __restrict__ rowinfo,
    const float* __restrict__ wslot,
    unsigned short* __restrict__ Hout,
    float* __restrict__ Out,
    int Kd, int Nd)
{
    const int b   = blockIdx.x;
    const int e   = b & 7;
    const int r   = b >> 3;
    const int mt0 = r & 7;
    const int nt  = r >> 3;
    const int ne  = counts[e];
    const int n0  = nt * 128;

    const int tid  = threadIdx.x;     // 0..511
    const int lane = tid & 63;
    const int wid  = tid >> 6;        // 0..7
    const int wm   = wid >> 1;        // 0..3 (M)
    const int wn   = wid & 1;         // 0..1 (N)

    __shared__ unsigned short S[2 * 16384];   // 2 buffers x (A 16KB + B 16KB)
    char* const Sb = (char*)S;

    const int l8 = lane >> 3;         // 0..7  (row-within-8 on store side)
    const int l7 = lane & 7;          // 0..7  (k-granule on store side)
    const int l15 = lane & 15;
    const int lhi = lane >> 4;        // 0..3

    // ---- store-side addresses (per-lane constants) ----
    // A rows w*16+m*8+l8; row&7 == l8 -> swizzled granule = (l7^l8)*16
    const int stA0 = (wid * 16 + 0 + l8) * 128 + ((l7 ^ l8) << 4);
    const int stA1 = (wid * 16 + 8 + l8) * 128 + ((l7 ^ l8) << 4);
    const int stB0 = 16384 + stA0;
    const int stB1 = 16384 + stA1;

    // ---- read-side swizzle pieces ----
    const int swz = (l15 & 7) << 4;   // (row&7)<<4, row = ...+l15
    const int kb0 = (0 * 64 + lhi * 16) ^ swz;   // kk = 0
    const int kb1 = (1 * 64 + lhi * 16) ^ swz;   // kk = 1

    // per-lane global source bases (elements); 8 consecutive lanes contiguous
    const unsigned short* const bbase =
        Bsrc + ((size_t)e * Nd + n0 + wid * 16 + l8) * Kd + l7 * 8;
    const size_t row8 = (size_t)8 * Kd;          // 8-row stride (elements)
    const int nt_k = Kd >> 6;                    // 16 (GEMM1) / 64 (GEMM2)
    const float* bg = bias + (size_t)e * Nd;

    #define COMPUTE_HALF(SOFF, KB)                                                     \
        do {                                                                           \
            bfrag av0 = *(const bfrag*)(Sb + (SOFF) + (wm * 32 +  0 + l15) * 128 + (KB)); \
            bfrag av1 = *(const bfrag*)(Sb + (SOFF) + (wm * 32 + 16 + l15) * 128 + (KB)); \
            bfrag bv0 = *(const bfrag*)(Sb + (SOFF) + 16384 + (wn * 64 +  0 + l15) * 128 + (KB)); \
            bfrag bv1 = *(const bfrag*)(Sb + (SOFF) + 16384 + (wn * 64 + 16 + l15) * 128 + (KB)); \
            bfrag bv2 = *(const bfrag*)(Sb + (SOFF) + 16384 + (wn * 64 + 32 + l15) * 128 + (KB)); \
            bfrag bv3 = *(const bfrag*)(Sb + (SOFF) + 16384 + (wn * 64 + 48 + l15) * 128 + (KB)); \
            __builtin_amdgcn_s_setprio(1);                                             \
            acc[0][0] = __builtin_amdgcn_mfma_f32_16x16x32_bf16(av0, bv0, acc[0][0], 0, 0, 0); \
            acc[0][1] = __builtin_amdgcn_mfma_f32_16x16x32_bf16(av0, bv1, acc[0][1], 0, 0, 0); \
            acc[0][2] = __builtin_amdgcn_mfma_f32_16x16x32_bf16(av0, bv2, acc[0][2], 0, 0, 0); \
            acc[0][3] = __builtin_amdgcn_mfma_f32_16x16x32_bf16(av0, bv3, acc[0][3], 0, 0, 0); \
            acc[1][0] = __builtin_amdgcn_mfma_f32_16x16x32_bf16(av1, bv0, acc[1][0], 0, 0, 0); \
            acc[1][1] = __builtin_amdgcn_mfma_f32_16x16x32_bf16(av1, bv1, acc[1][1], 0, 0, 0); \
            acc[1][2] = __builtin_amdgcn_mfma_f32_16x16x32_bf16(av1, bv2, acc[1][2], 0, 0, 0); \
            acc[1][3] = __builtin_amdgcn_mfma_f32_16x16x32_bf16(av1, bv3, acc[1][3], 0, 0, 0); \
            __builtin_amdgcn_s_setprio(0);                                             \
        } while (0)

    for (int mt = mt0; mt * 128 < ne; mt += 8) {
        const int growbase = offs[e] + mt * 128;
        const unsigned short* const abase =
            Asrc + (size_t)(growbase + wid * 16 + l8) * Kd + l7 * 8;

        f32x4 acc[2][4];
        #pragma unroll
        for (int i = 0; i < 2; i++)
            #pragma unroll
            for (int j = 0; j < 4; j++)
                acc[i][j] = (f32x4){0.f, 0.f, 0.f, 0.f};

        // ---- prologue: tiles 0,1 -> reg sets 0,1; write set0 -> buf0 ----
        int4 a0q0 = *(const int4*)(abase);
        int4 a0q1 = *(const int4*)(abase + row8);
        int4 b0q0 = *(const int4*)(bbase);
        int4 b0q1 = *(const int4*)(bbase + row8);
        int4 a1q0 = *(const int4*)(abase + 64);
        int4 a1q1 = *(const int4*)(abase + row8 + 64);
        int4 b1q0 = *(const int4*)(bbase + 64);
        int4 b1q1 = *(const int4*)(bbase + row8 + 64);
        *(int4*)(Sb + stA0) = a0q0;
        *(int4*)(Sb + stA1) = a0q1;
        *(int4*)(Sb + stB0) = b0q0;
        *(int4*)(Sb + stB1) = b0q1;
        asm volatile("s_waitcnt lgkmcnt(0)" ::: "memory");
        __builtin_amdgcn_s_barrier();

        for (int t = 0; t < nt_k; t += 2) {
            // ==== phase A: compute tile t (buf0); write tile t+1 -> buf1;
            //      issue loads tile t+2 -> set0 ====
            if (t + 2 < nt_k) {
                a0q0 = *(const int4*)(abase + (t + 2) * 64);
                a0q1 = *(const int4*)(abase + row8 + (t + 2) * 64);
                b0q0 = *(const int4*)(bbase + (t + 2) * 64);
                b0q1 = *(const int4*)(bbase + row8 + (t + 2) * 64);
            }
            COMPUTE_HALF(0, kb0);
            COMPUTE_HALF(0, kb1);
            *(int4*)(Sb + 32768 + stA0) = a1q0;
            *(int4*)(Sb + 32768 + stA1) = a1q1;
            *(int4*)(Sb + 32768 + stB0) = b1q0;
            *(int4*)(Sb + 32768 + stB1) = b1q1;
            asm volatile("s_waitcnt lgkmcnt(0)" ::: "memory");
            __builtin_amdgcn_s_barrier();

            // ==== phase B: compute tile t+1 (buf1); write tile t+2 -> buf0;
            //      issue loads tile t+3 -> set1 ====
            if (t + 3 < nt_k) {
                a1q0 = *(const int4*)(abase + (t + 3) * 64);
                a1q1 = *(const int4*)(abase + row8 + (t + 3) * 64);
                b1q0 = *(const int4*)(bbase + (t + 3) * 64);
                b1q1 = *(const int4*)(bbase + row8 + (t + 3) * 64);
            }
            COMPUTE_HALF(32768, kb0);
            COMPUTE_HALF(32768, kb1);
            if (t + 2 < nt_k) {
                *(int4*)(Sb + stA0) = a0q0;
                *(int4*)(Sb + stA1) = a0q1;
                *(int4*)(Sb + stB0) = b0q0;
                *(int4*)(Sb + stB1) = b0q1;
            }
            asm volatile("s_waitcnt lgkmcnt(0)" ::: "memory");
            __builtin_amdgcn_s_barrier();
        }

        // ---- epilogue (C/D layout: col = lane&15, row = (lane>>4)*4 + reg) ----
        #pragma unroll
        for (int i = 0; i < 2; i++) {
            #pragma unroll
            for (int rr = 0; rr < 4; rr++) {
                int mrow = wm * 32 + i * 16 + (lhi << 2) + rr;
                int pos = mt * 128 + mrow;
                if (pos >= ne) continue;
                if constexpr (EPI == 0) {
                    size_t rowoff = (size_t)(growbase + mrow) * Nd;
                    #pragma unroll
                    for (int j = 0; j < 4; j++) {
                        int col = n0 + wn * 64 + j * 16 + l15;
                        float y = acc[i][j][rr] + bg[col];
                        float gl = 0.5f * y * (1.f + erff(y * 0.70710678118654752f));
                        Hout[rowoff + col] = f2bf(gl);
                    }
                } else {
                    int info = rowinfo[growbase + mrow];
                    float wg = wslot[info];
                    float* op = Out + (size_t)(info >> 1) * Nd;
                    #pragma unroll
                    for (int j = 0; j < 4; j++) {
                        int col = n0 + wn * 64 + j * 16 + l15;
                        float y = acc[i][j][rr] + bg[col];
                        atomicAdd(op + col, wg * y);   // exactly 2 adds/elem -> deterministic
                    }
                }
            }
        }
    }
    #undef COMPUTE_HALF
}

// ---------------------------------------------------------------------------
extern "C" void kernel_launch(void* const* d_in, const int* in_sizes, int n_in,
                              void* d_out, int out_size, void* d_ws, size_t ws_size,
                              hipStream_t stream)
{
    (void)in_sizes; (void)n_in;
    const float* hidden   = (const float*)d_in[0];
    const float* rn_g     = (const float*)d_in[1];
    const float* rn_b     = (const float*)d_in[2];
    const float* router_w = (const float*)d_in[3];
    const float* router_b = (const float*)d_in[4];
    const float* ln_g     = (const float*)d_in[5];
    const float* ln_b     = (const float*)d_in[6];
    const float* w1       = (const float*)d_in[7];
    const float* b1       = (const float*)d_in[8];
    const float* w2       = (const float*)d_in[9];
    const float* b2       = (const float*)d_in[10];
    float* out = (float*)d_out;

    // workspace layout (bytes), total ~162.2 MB
    char* ws = (char*)d_ws;
    unsigned short* xhat   = (unsigned short*)ws;
    unsigned short* Agath  = (unsigned short*)(ws + 8388608);
    unsigned short* H      = (unsigned short*)(ws + 25690112);
    unsigned short* WT     = (unsigned short*)(ws + 94896128);
    int*   counts   = (int*)(ws + 162004992);
    int*   offs     = (int*)(ws + 162005024);
    int*   tok_slot = (int*)(ws + 162005056);
    int*   rowinfo  = (int*)(ws + 162136128);
    float* wslot    = (float*)(ws + 162169920);
    if (ws_size < 162202688) return;   // fail loudly (validation will catch it)

    hipMemsetAsync(counts, 0, 64, stream);                 // counts + offs
    hipMemsetAsync(d_out, 0, (size_t)out_size * sizeof(float), stream);

    // W1 [8][1024][4096] -> W1T [8][4096][1024]
    transpose_kernel<<<dim3(IDIM / 256, DDIM / 64, NEXP), 256, 0, stream>>>(w1, WT, DDIM, IDIM);
    router_kernel<<<T_TOK, 256, 0, stream>>>(hidden, rn_g, rn_b, router_w, router_b,
                                             xhat, counts, tok_slot, wslot);
    prefix_kernel<<<1, 64, 0, stream>>>(counts, offs);
    gather_kernel<<<dim3(T_TOK, NEXP), 256, 0, stream>>>(xhat, ln_g, ln_b, counts, offs,
                                                         tok_slot, Agath, rowinfo);
    // GEMM1: [rows x 1024] x [1024 x 4096] + b1, GELU -> H
    //   grid = 8 e x 8 mt0 x 32 nt (persistent mt loop inside)
    gemm_kernel<0><<<dim3(8 * 8 * (IDIM / 128)), 512, 0, stream>>>(
        Agath, WT, b1, counts, offs, rowinfo, wslot, H, nullptr, DDIM, IDIM);
    // W2 [8][4096][1024] -> W2T [8][1024][4096] (reuses WT buffer after GEMM1)
    transpose_kernel<<<dim3(DDIM / 256, IDIM / 64, NEXP), 256, 0, stream>>>(w2, WT, IDIM, DDIM);
    // GEMM2: [rows x 4096] x [4096 x 1024] + b2, *w, scatter-add -> out
    //   grid = 8 e x 8 mt0 x 8 nt
    gemm_kernel<1><<<dim3(8 * 8 * (DDIM / 128)), 512, 0, stream>>>(
        H, WT, b2, counts, offs, rowinfo, wslot, nullptr, out, IDIM, DDIM);
}

// Round 13
// 612.457 us; speedup vs baseline: 1.3611x; 1.3611x over previous
//
#include <hip/hip_runtime.h>
#include <hip/hip_bf16.h>
#include <stdint.h>

// Problem constants (B=2, L=2048 -> T=4096 tokens)
#define T_TOK 4096
#define DDIM  1024
#define IDIM  4096
#define NEXP  8
// padded row count for gathered matrices (worst-case 256-tile overhang)
#define GROWS (T_TOK*2 + 256)

typedef __attribute__((ext_vector_type(8))) short bfrag;   // 8 bf16 (4 VGPR)
typedef __attribute__((ext_vector_type(4))) float f32x4;   // MFMA accum

__device__ __forceinline__ unsigned short f2bf(float x) {
    unsigned int u = __float_as_uint(x);
    unsigned int r = u + 0x7FFFu + ((u >> 16) & 1u);   // RNE
    return (unsigned short)(r >> 16);
}
__device__ __forceinline__ float bf2f(unsigned short h) {
    return __uint_as_float(((unsigned int)h) << 16);
}

// ---------------------------------------------------------------------------
// K1: per-token layernorm stats + xhat (bf16), fp32 router logits, top-2,
//     softmax -> per-slot weights; builds per-expert token lists via atomics.
// ---------------------------------------------------------------------------
__global__ __launch_bounds__(256) void router_kernel(
    const float* __restrict__ x,
    const float* __restrict__ rng, const float* __restrict__ rnb,
    const float* __restrict__ rw,  const float* __restrict__ rb,
    unsigned short* __restrict__ xhat,
    int* __restrict__ counts, int* __restrict__ tok_slot,
    float* __restrict__ wslot)
{
    const int t = blockIdx.x;
    const int tid = threadIdx.x;
    const int lane = tid & 63, wid = tid >> 6;

    float4 v = *(const float4*)(x + (size_t)t * DDIM + tid * 4);
    float s1 = v.x + v.y + v.z + v.w;
    float s2 = v.x*v.x + v.y*v.y + v.z*v.z + v.w*v.w;
    #pragma unroll
    for (int m = 32; m; m >>= 1) { s1 += __shfl_xor(s1, m, 64); s2 += __shfl_xor(s2, m, 64); }

    __shared__ float red[8];
    __shared__ float pl[4][8];
    __shared__ float bcast[2];
    if (lane == 0) { red[wid] = s1; red[wid + 4] = s2; }
    __syncthreads();
    if (tid == 0) {
        float S1 = red[0] + red[1] + red[2] + red[3];
        float S2 = red[4] + red[5] + red[6] + red[7];
        float mean = S1 * (1.f / 1024.f);
        float var  = S2 * (1.f / 1024.f) - mean * mean;
        bcast[0] = mean; bcast[1] = rsqrtf(var + 1e-5f);
    }
    __syncthreads();
    const float mean = bcast[0], rinv = bcast[1];

    float4 xh = { (v.x - mean) * rinv, (v.y - mean) * rinv,
                  (v.z - mean) * rinv, (v.w - mean) * rinv };
    ushort4 hx = { f2bf(xh.x), f2bf(xh.y), f2bf(xh.z), f2bf(xh.w) };
    *(ushort4*)(xhat + (size_t)t * DDIM + tid * 4) = hx;

    // router layernorm affine + logits (kept fp32 to match reference top-k)
    float4 g = *(const float4*)(rng + tid * 4);
    float4 b = *(const float4*)(rnb + tid * 4);
    float4 nm = { xh.x*g.x + b.x, xh.y*g.y + b.y, xh.z*g.z + b.z, xh.w*g.w + b.w };
    float p[8];
    #pragma unroll
    for (int e = 0; e < 8; e++) {
        float4 w = *(const float4*)(rw + e * DDIM + tid * 4);
        p[e] = nm.x*w.x + nm.y*w.y + nm.z*w.z + nm.w*w.w;
    }
    #pragma unroll
    for (int m = 32; m; m >>= 1) {
        #pragma unroll
        for (int e = 0; e < 8; e++) p[e] += __shfl_xor(p[e], m, 64);
    }
    if (lane == 0) {
        #pragma unroll
        for (int e = 0; e < 8; e++) pl[wid][e] = p[e];
    }
    __syncthreads();
    if (tid == 0) {
        float l[8];
        #pragma unroll
        for (int e = 0; e < 8; e++) l[e] = pl[0][e] + pl[1][e] + pl[2][e] + pl[3][e] + rb[e];
        int e0 = 0; float v0 = l[0];
        for (int e = 1; e < 8; e++) if (l[e] > v0) { v0 = l[e]; e0 = e; }
        int e1 = (e0 == 0) ? 1 : 0; float v1 = l[e1];
        for (int e = 0; e < 8; e++) if (e != e0 && l[e] > v1) { v1 = l[e]; e1 = e; }
        float ex = expf(v1 - v0);
        float w0 = 1.f / (1.f + ex);
        float w1 = ex * w0;
        int p0 = atomicAdd(&counts[e0], 1);
        tok_slot[e0 * T_TOK + p0] = (t << 1);
        int p1 = atomicAdd(&counts[e1], 1);
        tok_slot[e1 * T_TOK + p1] = (t << 1) | 1;
        wslot[t * 2]     = w0;
        wslot[t * 2 + 1] = w1;
    }
}

// K2: tiny exclusive prefix over 8 expert counts
__global__ void prefix_kernel(const int* __restrict__ counts, int* __restrict__ offs)
{
    if (threadIdx.x == 0) {
        int a = 0;
        for (int e = 0; e < 8; e++) { offs[e] = a; a += counts[e]; }
    }
}

// ---------------------------------------------------------------------------
// K3: build compacted per-expert A matrix: Agath[off[e]+pos][d] =
//     bf16( xhat[t][d]*ln_g[e][d] + ln_b[e][d] ), plus rowinfo for scatter.
// ---------------------------------------------------------------------------
__global__ __launch_bounds__(256) void gather_kernel(
    const unsigned short* __restrict__ xhat,
    const float* __restrict__ lng, const float* __restrict__ lnb,
    const int* __restrict__ counts, const int* __restrict__ offs,
    const int* __restrict__ tok_slot,
    unsigned short* __restrict__ Agath, int* __restrict__ rowinfo)
{
    const int e = blockIdx.y, pos = blockIdx.x;
    if (pos >= counts[e]) return;
    const int grow = offs[e] + pos;
    const int info = tok_slot[e * T_TOK + pos];
    if (threadIdx.x == 0) rowinfo[grow] = info;
    const int t = info >> 1;
    const int d = threadIdx.x * 4;
    ushort4 hx = *(const ushort4*)(xhat + (size_t)t * DDIM + d);
    float4 g = *(const float4*)(lng + (size_t)e * DDIM + d);
    float4 b = *(const float4*)(lnb + (size_t)e * DDIM + d);
    ushort4 o = { f2bf(bf2f(hx.x) * g.x + b.x),
                  f2bf(bf2f(hx.y) * g.y + b.y),
                  f2bf(bf2f(hx.z) * g.z + b.z),
                  f2bf(bf2f(hx.w) * g.w + b.w) };
    *(ushort4*)(Agath + (size_t)grow * DDIM + d) = o;
}

// ---------------------------------------------------------------------------
// K4: transpose+convert weights: W [E][Kd][Nd] fp32 -> WT [E][Nd][Kd] bf16.
// ---------------------------------------------------------------------------
__global__ __launch_bounds__(256) void transpose_kernel(
    const float* __restrict__ W, unsigned short* __restrict__ WT,
    int Kd, int Nd)
{
    const int e  = blockIdx.z;
    const int k0 = blockIdx.y * 64;
    const int n  = blockIdx.x * 256 + threadIdx.x;
    const float* src = W + (size_t)e * Kd * Nd + (size_t)k0 * Nd + n;
    unsigned short* dst = WT + ((size_t)e * Nd + n) * Kd + k0;
    unsigned short buf[64];
    #pragma unroll
    for (int j = 0; j < 64; j++)
        buf[j] = f2bf(src[(size_t)j * Nd]);
    #pragma unroll
    for (int c = 0; c < 8; c++)
        *(int4*)(dst + c * 8) = *(const int4*)(buf + c * 8);
}

// ---------------------------------------------------------------------------
// GEMM, reg-staged 2-phase pipeline, per-wave 64x64 (reuse-ratio fix):
//
//   GEOMETRY (the one change vs R12): 128x128 tile, 4 waves (2Mx2N), per-wave
//   64x64 output, acc[4][4]. Per K-tile per block: LDS frag reads = 4 waves x
//   16KB = 64KB (vs 96KB for 8x 32x64 waves) for the SAME 2.1e6 FLOP ->
//   FLOP/LDS-byte doubles (m97's proven ratio). MFMA wall per SIMD doubles
//   (32 MFMA/wave). R10-12's 32x64 waves were structurally LDS/issue-bound
//   at ~10% MfmaUtil regardless of transport.
//
//   Transport (kept from R12): coalesced global_load_dwordx4 (8 consecutive
//   lanes = 128B contiguous), reg-staged (no LDS-DMA aliasing drain),
//   XOR-swizzled LDS [row][k] (conflicts=0 measured):
//       byte(row, g) = row*128 + ((g*16) ^ ((row&7)<<4)),  g = k>>3
//   2 reg sets / 2 LDS buffers; loads t+2 issue at phase start; ds_write t+1
//   after MFMAs; ONE lgkmcnt(0)+s_barrier per K-tile; no vmcnt drains.
//
// Grid: 1-D, e=b&7 (XCD pin), r=b>>3, mt0=r&7, nt=r>>3; persistent-mt loop.
// EPI=0: +b1, exact GELU -> H (bf16). EPI=1: +b2, *combine-w, atomicAdd out.
// ---------------------------------------------------------------------------
template<int EPI>
__global__ __launch_bounds__(256, 2) void gemm_kernel(
    const unsigned short* __restrict__ Asrc,
    const unsigned short* __restrict__ Bsrc,
    const float* __restrict__ bias,
    const int* __restrict__ counts,
    const int* __restrict__ offs,
    const int* __restrict__ rowinfo,
    const float* __restrict__ wslot,
    unsigned short* __restrict__ Hout,
    float* __restrict__ Out,
    int Kd, int Nd)
{
    const int b   = blockIdx.x;
    const int e   = b & 7;
    const int r   = b >> 3;
    const int mt0 = r & 7;
    const int nt  = r >> 3;
    const int ne  = counts[e];
    const int n0  = nt * 128;

    const int tid  = threadIdx.x;     // 0..255
    const int lane = tid & 63;
    const int wid  = tid >> 6;        // 0..3
    const int wm   = wid >> 1;        // 0..1 (M)
    const int wn   = wid & 1;         // 0..1 (N)

    __shared__ unsigned short S[2 * 16384];   // 2 buffers x (A 16KB + B 16KB)
    char* const Sb = (char*)S;

    const int l8  = lane >> 3;        // 0..7 (row-within-8, store side)
    const int l7  = lane & 7;         // 0..7 (k-granule, store side)
    const int l15 = lane & 15;
    const int lhi = lane >> 4;        // 0..3

    // ---- store-side LDS addresses: wave wid stages rows wid*32 + m*8 + l8 ----
    // row&7 == l8 -> swizzled granule (l7^l8)
    const int st0 = (wid * 32 +  0 + l8) * 128 + ((l7 ^ l8) << 4);
    const int st1 = (wid * 32 +  8 + l8) * 128 + ((l7 ^ l8) << 4);
    const int st2 = (wid * 32 + 16 + l8) * 128 + ((l7 ^ l8) << 4);
    const int st3 = (wid * 32 + 24 + l8) * 128 + ((l7 ^ l8) << 4);

    // ---- read-side swizzle: byte = (kk*64 + lhi*16) ^ ((row&7)<<4), row&7 = l15&7
    const int swz = (l15 & 7) << 4;
    const int kb0 = (0 * 64 + lhi * 16) ^ swz;
    const int kb1 = (1 * 64 + lhi * 16) ^ swz;

    // per-lane global source bases (elements); 8 consecutive lanes contiguous
    const unsigned short* const bbase =
        Bsrc + ((size_t)e * Nd + n0 + wid * 32 + l8) * Kd + l7 * 8;
    const size_t row8 = (size_t)8 * Kd;          // 8-row stride (elements)
    const int nt_k = Kd >> 6;                    // 16 (GEMM1) / 64 (GEMM2)
    const float* bg = bias + (size_t)e * Nd;

    // one kk-half: 4 A frags + 4 B frags + 16 MFMA
    #define COMPUTE_HALF(SOFF, KB)                                                     \
        do {                                                                           \
            bfrag av0 = *(const bfrag*)(Sb + (SOFF) + (wm * 64 +  0 + l15) * 128 + (KB)); \
            bfrag av1 = *(const bfrag*)(Sb + (SOFF) + (wm * 64 + 16 + l15) * 128 + (KB)); \
            bfrag av2 = *(const bfrag*)(Sb + (SOFF) + (wm * 64 + 32 + l15) * 128 + (KB)); \
            bfrag av3 = *(const bfrag*)(Sb + (SOFF) + (wm * 64 + 48 + l15) * 128 + (KB)); \
            bfrag bv0 = *(const bfrag*)(Sb + (SOFF) + 16384 + (wn * 64 +  0 + l15) * 128 + (KB)); \
            bfrag bv1 = *(const bfrag*)(Sb + (SOFF) + 16384 + (wn * 64 + 16 + l15) * 128 + (KB)); \
            bfrag bv2 = *(const bfrag*)(Sb + (SOFF) + 16384 + (wn * 64 + 32 + l15) * 128 + (KB)); \
            bfrag bv3 = *(const bfrag*)(Sb + (SOFF) + 16384 + (wn * 64 + 48 + l15) * 128 + (KB)); \
            __builtin_amdgcn_s_setprio(1);                                             \
            acc[0][0] = __builtin_amdgcn_mfma_f32_16x16x32_bf16(av0, bv0, acc[0][0], 0, 0, 0); \
            acc[0][1] = __builtin_amdgcn_mfma_f32_16x16x32_bf16(av0, bv1, acc[0][1], 0, 0, 0); \
            acc[0][2] = __builtin_amdgcn_mfma_f32_16x16x32_bf16(av0, bv2, acc[0][2], 0, 0, 0); \
            acc[0][3] = __builtin_amdgcn_mfma_f32_16x16x32_bf16(av0, bv3, acc[0][3], 0, 0, 0); \
            acc[1][0] = __builtin_amdgcn_mfma_f32_16x16x32_bf16(av1, bv0, acc[1][0], 0, 0, 0); \
            acc[1][1] = __builtin_amdgcn_mfma_f32_16x16x32_bf16(av1, bv1, acc[1][1], 0, 0, 0); \
            acc[1][2] = __builtin_amdgcn_mfma_f32_16x16x32_bf16(av1, bv2, acc[1][2], 0, 0, 0); \
            acc[1][3] = __builtin_amdgcn_mfma_f32_16x16x32_bf16(av1, bv3, acc[1][3], 0, 0, 0); \
            acc[2][0] = __builtin_amdgcn_mfma_f32_16x16x32_bf16(av2, bv0, acc[2][0], 0, 0, 0); \
            acc[2][1] = __builtin_amdgcn_mfma_f32_16x16x32_bf16(av2, bv1, acc[2][1], 0, 0, 0); \
            acc[2][2] = __builtin_amdgcn_mfma_f32_16x16x32_bf16(av2, bv2, acc[2][2], 0, 0, 0); \
            acc[2][3] = __builtin_amdgcn_mfma_f32_16x16x32_bf16(av2, bv3, acc[2][3], 0, 0, 0); \
            acc[3][0] = __builtin_amdgcn_mfma_f32_16x16x32_bf16(av3, bv0, acc[3][0], 0, 0, 0); \
            acc[3][1] = __builtin_amdgcn_mfma_f32_16x16x32_bf16(av3, bv1, acc[3][1], 0, 0, 0); \
            acc[3][2] = __builtin_amdgcn_mfma_f32_16x16x32_bf16(av3, bv2, acc[3][2], 0, 0, 0); \
            acc[3][3] = __builtin_amdgcn_mfma_f32_16x16x32_bf16(av3, bv3, acc[3][3], 0, 0, 0); \
            __builtin_amdgcn_s_setprio(0);                                             \
        } while (0)

    // load one tile's 4 A + 4 B quads into a named reg set
    #define LOADSET(SET, TOFF)                                                         \
        do {                                                                           \
            a##SET##q0 = *(const int4*)(abase + (TOFF));                               \
            a##SET##q1 = *(const int4*)(abase + row8 + (TOFF));                        \
            a##SET##q2 = *(const int4*)(abase + 2 * row8 + (TOFF));                    \
            a##SET##q3 = *(const int4*)(abase + 3 * row8 + (TOFF));                    \
            b##SET##q0 = *(const int4*)(bbase + (TOFF));                               \
            b##SET##q1 = *(const int4*)(bbase + row8 + (TOFF));                        \
            b##SET##q2 = *(const int4*)(bbase + 2 * row8 + (TOFF));                    \
            b##SET##q3 = *(const int4*)(bbase + 3 * row8 + (TOFF));                    \
        } while (0)

    #define WRITESET(SET, SOFF)                                                        \
        do {                                                                           \
            *(int4*)(Sb + (SOFF) + st0)         = a##SET##q0;                          \
            *(int4*)(Sb + (SOFF) + st1)         = a##SET##q1;                          \
            *(int4*)(Sb + (SOFF) + st2)         = a##SET##q2;                          \
            *(int4*)(Sb + (SOFF) + st3)         = a##SET##q3;                          \
            *(int4*)(Sb + (SOFF) + 16384 + st0) = b##SET##q0;                          \
            *(int4*)(Sb + (SOFF) + 16384 + st1) = b##SET##q1;                          \
            *(int4*)(Sb + (SOFF) + 16384 + st2) = b##SET##q2;                          \
            *(int4*)(Sb + (SOFF) + 16384 + st3) = b##SET##q3;                          \
        } while (0)

    for (int mt = mt0; mt * 128 < ne; mt += 8) {
        const int growbase = offs[e] + mt * 128;
        const unsigned short* const abase =
            Asrc + (size_t)(growbase + wid * 32 + l8) * Kd + l7 * 8;

        f32x4 acc[4][4];
        #pragma unroll
        for (int i = 0; i < 4; i++)
            #pragma unroll
            for (int j = 0; j < 4; j++)
                acc[i][j] = (f32x4){0.f, 0.f, 0.f, 0.f};

        int4 a0q0, a0q1, a0q2, a0q3, b0q0, b0q1, b0q2, b0q3;
        int4 a1q0, a1q1, a1q2, a1q3, b1q0, b1q1, b1q2, b1q3;

        // ---- prologue: tiles 0,1 -> reg sets 0,1; write set0 -> buf0 ----
        LOADSET(0, 0);
        LOADSET(1, 64);
        WRITESET(0, 0);
        asm volatile("s_waitcnt lgkmcnt(0)" ::: "memory");
        __builtin_amdgcn_s_barrier();

        for (int t = 0; t < nt_k; t += 2) {
            // ==== phase A: compute tile t (buf0); write t+1 -> buf1; load t+2 -> set0
            if (t + 2 < nt_k) LOADSET(0, (t + 2) * 64);
            COMPUTE_HALF(0, kb0);
            COMPUTE_HALF(0, kb1);
            WRITESET(1, 32768);
            asm volatile("s_waitcnt lgkmcnt(0)" ::: "memory");
            __builtin_amdgcn_s_barrier();

            // ==== phase B: compute tile t+1 (buf1); write t+2 -> buf0; load t+3 -> set1
            if (t + 3 < nt_k) LOADSET(1, (t + 3) * 64);
            COMPUTE_HALF(32768, kb0);
            COMPUTE_HALF(32768, kb1);
            if (t + 2 < nt_k) WRITESET(0, 0);
            asm volatile("s_waitcnt lgkmcnt(0)" ::: "memory");
            __builtin_amdgcn_s_barrier();
        }

        // ---- epilogue (C/D layout: col = lane&15, row = (lane>>4)*4 + reg) ----
        #pragma unroll
        for (int i = 0; i < 4; i++) {
            #pragma unroll
            for (int rr = 0; rr < 4; rr++) {
                int mrow = wm * 64 + i * 16 + (lhi << 2) + rr;
                int pos = mt * 128 + mrow;
                if (pos >= ne) continue;
                if constexpr (EPI == 0) {
                    size_t rowoff = (size_t)(growbase + mrow) * Nd;
                    #pragma unroll
                    for (int j = 0; j < 4; j++) {
                        int col = n0 + wn * 64 + j * 16 + l15;
                        float y = acc[i][j][rr] + bg[col];
                        float gl = 0.5f * y * (1.f + erff(y * 0.70710678118654752f));
                        Hout[rowoff + col] = f2bf(gl);
                    }
                } else {
                    int info = rowinfo[growbase + mrow];
                    float wg = wslot[info];
                    float* op = Out + (size_t)(info >> 1) * Nd;
                    #pragma unroll
                    for (int j = 0; j < 4; j++) {
                        int col = n0 + wn * 64 + j * 16 + l15;
                        float y = acc[i][j][rr] + bg[col];
                        atomicAdd(op + col, wg * y);   // exactly 2 adds/elem -> deterministic
                    }
                }
            }
        }
    }
    #undef COMPUTE_HALF
    #undef LOADSET
    #undef WRITESET
}

// ---------------------------------------------------------------------------
extern "C" void kernel_launch(void* const* d_in, const int* in_sizes, int n_in,
                              void* d_out, int out_size, void* d_ws, size_t ws_size,
                              hipStream_t stream)
{
    (void)in_sizes; (void)n_in;
    const float* hidden   = (const float*)d_in[0];
    const float* rn_g     = (const float*)d_in[1];
    const float* rn_b     = (const float*)d_in[2];
    const float* router_w = (const float*)d_in[3];
    const float* router_b = (const float*)d_in[4];
    const float* ln_g     = (const float*)d_in[5];
    const float* ln_b     = (const float*)d_in[6];
    const float* w1       = (const float*)d_in[7];
    const float* b1       = (const float*)d_in[8];
    const float* w2       = (const float*)d_in[9];
    const float* b2       = (const float*)d_in[10];
    float* out = (float*)d_out;

    // workspace layout (bytes), total ~162.2 MB
    char* ws = (char*)d_ws;
    unsigned short* xhat   = (unsigned short*)ws;
    unsigned short* Agath  = (unsigned short*)(ws + 8388608);
    unsigned short* H      = (unsigned short*)(ws + 25690112);
    unsigned short* WT     = (unsigned short*)(ws + 94896128);
    int*   counts   = (int*)(ws + 162004992);
    int*   offs     = (int*)(ws + 162005024);
    int*   tok_slot = (int*)(ws + 162005056);
    int*   rowinfo  = (int*)(ws + 162136128);
    float* wslot    = (float*)(ws + 162169920);
    if (ws_size < 162202688) return;   // fail loudly (validation will catch it)

    hipMemsetAsync(counts, 0, 64, stream);                 // counts + offs
    hipMemsetAsync(d_out, 0, (size_t)out_size * sizeof(float), stream);

    // W1 [8][1024][4096] -> W1T [8][4096][1024]
    transpose_kernel<<<dim3(IDIM / 256, DDIM / 64, NEXP), 256, 0, stream>>>(w1, WT, DDIM, IDIM);
    router_kernel<<<T_TOK, 256, 0, stream>>>(hidden, rn_g, rn_b, router_w, router_b,
                                             xhat, counts, tok_slot, wslot);
    prefix_kernel<<<1, 64, 0, stream>>>(counts, offs);
    gather_kernel<<<dim3(T_TOK, NEXP), 256, 0, stream>>>(xhat, ln_g, ln_b, counts, offs,
                                                         tok_slot, Agath, rowinfo);
    // GEMM1: [rows x 1024] x [1024 x 4096] + b1, GELU -> H
    //   grid = 8 e x 8 mt0 x 32 nt (persistent mt loop inside)
    gemm_kernel<0><<<dim3(8 * 8 * (IDIM / 128)), 256, 0, stream>>>(
        Agath, WT, b1, counts, offs, rowinfo, wslot, H, nullptr, DDIM, IDIM);
    // W2 [8][4096][1024] -> W2T [8][1024][4096] (reuses WT buffer after GEMM1)
    transpose_kernel<<<dim3(DDIM / 256, IDIM / 64, NEXP), 256, 0, stream>>>(w2, WT, IDIM, DDIM);
    // GEMM2: [rows x 4096] x [4096 x 1024] + b2, *w, scatter-add -> out
    //   grid = 8 e x 8 mt0 x 8 nt
    gemm_kernel<1><<<dim3(8 * 8 * (DDIM / 128)), 256, 0, stream>>>(
        H, WT, b2, counts, offs, rowinfo, wslot, nullptr, out, IDIM, DDIM);
}